// Round 2
// baseline (11582.990 us; speedup 1.0000x reference)
//
#include <hip/hip_runtime.h>

#define NB 4096
#define ND 64
#define NH 256
#define NT 50
#define ROWS 16   // rows per block

// LDS layout (floats): sW2 [256][64] then sZ [16][256]; yi overlays sZ cols 0..63.
// Total = 16384 + 4096 floats = 81920 bytes = exactly 2 blocks / 160KB CU.
#define W2S 64
#define ZS  256
#define Z_OFF (NH * W2S)                  // 16384
#define LDS_FLOATS (Z_OFF + ROWS * ZS)    // 20480 -> 81920 bytes

__device__ __forceinline__ float fast_tanh(float x) {
  // tanh(x) = 1 - 2/(exp(2x)+1); safe at +-inf
  float e = __expf(2.0f * x);
  return 1.0f - 2.0f * __builtin_amdgcn_rcpf(e + 1.0f);
}

#define AXPY_IP(acc, c, v)                                                     \
  do {                                                                         \
    acc.x = fmaf((c), (v).x, acc.x);                                           \
    acc.y = fmaf((c), (v).y, acc.y);                                           \
    acc.z = fmaf((c), (v).z, acc.z);                                           \
    acc.w = fmaf((c), (v).w, acc.w);                                           \
  } while (0)

extern "C" __global__ void __launch_bounds__(256, 2)
ode_kernel(const float* __restrict__ y0,
           const float* __restrict__ tt,
           const float* __restrict__ W1,
           const float* __restrict__ b1,
           const float* __restrict__ W2,
           const float* __restrict__ b2,
           float* __restrict__ out)
{
  extern __shared__ float smem[];
  float* __restrict__ sW2 = smem;          // [NH][W2S]
  float* __restrict__ sZ  = smem + Z_OFF;  // [ROWS][ZS]; yi overlays cols 0..63

  const int tid = threadIdx.x;   // doubles as hidden-unit index j for GEMM1
  const int rr  = tid >> 4;      // row-in-block (0..15)
  const int cc  = tid & 15;      // dim-quad (0..15) -> dims 4*cc..4*cc+3
  const int row = (int)blockIdx.x * ROWS + rr;

  // Stage W2 into LDS (coalesced, no padding)
  for (int i = tid; i < NH * ND; i += 256) {
    sW2[i] = W2[i];
  }

  // W1 column tid into registers (coalesced: lanes read consecutive j)
  float w1c[ND];
#pragma unroll
  for (int d = 0; d < ND; ++d) w1c[d] = W1[d * NH + tid];
  const float b1j = b1[tid];
  const float4 b2q = *(const float4*)&b2[cc * 4];

  // state slice: y[row][4cc..4cc+3]
  float4 y4 = *(const float4*)&y0[row * ND + cc * 4];
  *(float4*)&out[row * ND + cc * 4] = y4;   // out[0] = y0

  __syncthreads();  // sW2 ready (also first B1 below would cover, kept for clarity)

  // f(yi) = tanh(yi @ W1 + b1) @ W2 + b2, returns this thread's 4-dim slice.
  // Schedule: B1 (prev z-reads done) | write yi | B2 | GEMM1 | B3 (yi-reads
  // done) | write z | B4 | GEMM2.
  auto feval = [&](float4 yiv) -> float4 {
    __syncthreads();  // B1: all GEMM2 reads of previous z complete
    *(float4*)&sZ[rr * ZS + cc * 4] = yiv;
    __syncthreads();  // B2: yi visible

    // GEMM1: z_j[r] for all 16 rows, j = tid, W1 column in registers.
    // Reads are wave-uniform broadcasts (conflict-free), immediate offsets.
    float z[ROWS];
#pragma unroll
    for (int r = 0; r < ROWS; ++r) z[r] = b1j;
#pragma unroll
    for (int db = 0; db < 16; ++db) {
      const float wa = w1c[db * 4 + 0];
      const float wb = w1c[db * 4 + 1];
      const float wc = w1c[db * 4 + 2];
      const float wd = w1c[db * 4 + 3];
#pragma unroll
      for (int r = 0; r < ROWS; ++r) {
        const float4 a = *(const float4*)&sZ[r * ZS + db * 4];
        z[r] = fmaf(a.x, wa, z[r]);
        z[r] = fmaf(a.y, wb, z[r]);
        z[r] = fmaf(a.z, wc, z[r]);
        z[r] = fmaf(a.w, wd, z[r]);
      }
    }
#pragma unroll
    for (int r = 0; r < ROWS; ++r) z[r] = fast_tanh(z[r]);

    __syncthreads();  // B3: all yi reads complete; safe to overwrite cols 0..63
#pragma unroll
    for (int r = 0; r < ROWS; ++r) sZ[r * ZS + tid] = z[r];
    __syncthreads();  // B4: z visible

    // GEMM2: out[rr][4cc..+3] = sum_j z[rr][j] * W2[j][4cc..+3] + b2
    // All reads single-base + immediate offset (max 65280 <= 65535).
    float o0 = b2q.x, o1 = b2q.y, o2 = b2q.z, o3 = b2q.w;
    const float* __restrict__ zrow = sZ + rr * ZS;
    const float* __restrict__ wcol = sW2 + cc * 4;
#pragma unroll 4
    for (int jb = 0; jb < NH; jb += 4) {
      const float4 zv = *(const float4*)&zrow[jb];
      const float4 wA = *(const float4*)&wcol[(jb + 0) * W2S];
      const float4 wB = *(const float4*)&wcol[(jb + 1) * W2S];
      const float4 wC = *(const float4*)&wcol[(jb + 2) * W2S];
      const float4 wD = *(const float4*)&wcol[(jb + 3) * W2S];
      o0 = fmaf(zv.x, wA.x, o0); o1 = fmaf(zv.x, wA.y, o1);
      o2 = fmaf(zv.x, wA.z, o2); o3 = fmaf(zv.x, wA.w, o3);
      o0 = fmaf(zv.y, wB.x, o0); o1 = fmaf(zv.y, wB.y, o1);
      o2 = fmaf(zv.y, wB.z, o2); o3 = fmaf(zv.y, wB.w, o3);
      o0 = fmaf(zv.z, wC.x, o0); o1 = fmaf(zv.z, wC.y, o1);
      o2 = fmaf(zv.z, wC.z, o2); o3 = fmaf(zv.z, wC.w, o3);
      o0 = fmaf(zv.w, wD.x, o0); o1 = fmaf(zv.w, wD.y, o1);
      o2 = fmaf(zv.w, wD.z, o2); o3 = fmaf(zv.w, wD.w, o3);
    }
    return make_float4(o0, o1, o2, o3);
  };

  // Dormand-Prince 5(4) tableau (5th-order solution row)
  const float A10 = (float)(1.0 / 5.0);
  const float A20 = (float)(3.0 / 40.0),      A21 = (float)(9.0 / 40.0);
  const float A30 = (float)(44.0 / 45.0),     A31 = (float)(-56.0 / 15.0),
              A32 = (float)(32.0 / 9.0);
  const float A40 = (float)(19372.0 / 6561.0), A41 = (float)(-25360.0 / 2187.0),
              A42 = (float)(64448.0 / 6561.0), A43 = (float)(-212.0 / 729.0);
  const float A50 = (float)(9017.0 / 3168.0),  A51 = (float)(-355.0 / 33.0),
              A52 = (float)(46732.0 / 5247.0), A53 = (float)(49.0 / 176.0),
              A54 = (float)(-5103.0 / 18656.0);
  const float B0 = (float)(35.0 / 384.0),      B2 = (float)(500.0 / 1113.0),
              B3 = (float)(125.0 / 192.0),     B4 = (float)(-2187.0 / 6784.0),
              B5 = (float)(11.0 / 84.0);

  for (int ti = 0; ti < NT - 1; ++ti) {
    const float dt = (tt[ti + 1] - tt[ti]) * 0.25f;  // /SUBSTEPS, exact pow2
    for (int ss = 0; ss < 4; ++ss) {
      float4 yi;
      const float4 k0 = feval(y4);

      yi = y4; AXPY_IP(yi, dt * A10, k0);
      const float4 k1 = feval(yi);

      yi = y4; AXPY_IP(yi, dt * A20, k0); AXPY_IP(yi, dt * A21, k1);
      const float4 k2 = feval(yi);

      yi = y4; AXPY_IP(yi, dt * A30, k0); AXPY_IP(yi, dt * A31, k1);
      AXPY_IP(yi, dt * A32, k2);
      const float4 k3 = feval(yi);

      yi = y4; AXPY_IP(yi, dt * A40, k0); AXPY_IP(yi, dt * A41, k1);
      AXPY_IP(yi, dt * A42, k2); AXPY_IP(yi, dt * A43, k3);
      const float4 k4 = feval(yi);

      yi = y4; AXPY_IP(yi, dt * A50, k0); AXPY_IP(yi, dt * A51, k1);
      AXPY_IP(yi, dt * A52, k2); AXPY_IP(yi, dt * A53, k3);
      AXPY_IP(yi, dt * A54, k4);
      const float4 k5 = feval(yi);

      // y_new = y + dt*(B0*k0 + B2*k2 + B3*k3 + B4*k4 + B5*k5)   (B1 = 0)
      AXPY_IP(y4, dt * B0, k0);
      AXPY_IP(y4, dt * B2, k2);
      AXPY_IP(y4, dt * B3, k3);
      AXPY_IP(y4, dt * B4, k4);
      AXPY_IP(y4, dt * B5, k5);
    }
    *(float4*)&out[(size_t)(ti + 1) * NB * ND + row * ND + cc * 4] = y4;
  }
}

extern "C" void kernel_launch(void* const* d_in, const int* in_sizes, int n_in,
                              void* d_out, int out_size, void* d_ws, size_t ws_size,
                              hipStream_t stream) {
  const float* y0 = (const float*)d_in[0];
  const float* tt = (const float*)d_in[1];
  const float* W1 = (const float*)d_in[2];
  const float* b1 = (const float*)d_in[3];
  const float* W2 = (const float*)d_in[4];
  const float* b2 = (const float*)d_in[5];
  float* out = (float*)d_out;

  const size_t lds_bytes = (size_t)LDS_FLOATS * sizeof(float);  // 81920 B
  hipFuncSetAttribute((const void*)ode_kernel,
                      hipFuncAttributeMaxDynamicSharedMemorySize,
                      (int)lds_bytes);
  hipLaunchKernelGGL(ode_kernel, dim3(NB / ROWS), dim3(256), lds_bytes, stream,
                     y0, tt, W1, b1, W2, b2, out);
}

// Round 3
// 10121.273 us; speedup vs baseline: 1.1444x; 1.1444x over previous
//
#include <hip/hip_runtime.h>

#define NB 4096
#define ND 64
#define NH 256
#define NT 50
#define ROWS 8
#define THREADS 512
#define GRID (NB / ROWS)   // 512 blocks -> exactly 2 per CU

#define YIS 68   // yi row stride (floats)
#define ZS  260  // z row stride (floats)

__device__ __forceinline__ float fast_tanh(float x) {
  // tanh(x) = 1 - 2/(exp(2x)+1); safe at +-inf
  float e = __expf(2.0f * x);
  return 1.0f - 2.0f * __builtin_amdgcn_rcpf(e + 1.0f);
}

extern "C" __global__ void __launch_bounds__(THREADS, 4)
ode_kernel(const float* __restrict__ y0,
           const float* __restrict__ tt,
           const float* __restrict__ W1,
           const float* __restrict__ b1,
           const float* __restrict__ W2,
           const float* __restrict__ b2,
           float* __restrict__ out)
{
  __shared__ float sYI[ROWS * YIS];        // 544 floats
  __shared__ float sZ[ROWS * ZS];          // 2080 floats
  __shared__ float sRed[8 * ROWS * ND];    // 4096 floats (16 KB)
  // total 26880 B static LDS -> never the occupancy limiter

  const int tid = threadIdx.x;
  // GEMM1 role: hidden column j1, d-half dh
  const int j1 = tid >> 1;
  const int dh = tid & 1;
  // GEMM2/state role: wave id = state row = j-chunk; d = dim
  const int wv = tid >> 6;
  const int d  = tid & 63;
  const int row = (int)blockIdx.x * ROWS + wv;

  // W1 slice in registers: W1[dh*32+dd][j1]
  float w1c[32];
#pragma unroll
  for (int dd = 0; dd < 32; ++dd) w1c[dd] = W1[(dh * 32 + dd) * NH + j1];
  const float b1j = b1[j1];

  // W2 slice in registers: W2[wv*32+jj][d]  (W2 never goes to LDS)
  float w2r[32];
#pragma unroll
  for (int jj = 0; jj < 32; ++jj) w2r[jj] = W2[(wv * 32 + jj) * ND + d];
  const float b2d = b2[d];

  // scalar state: y[row][d], exactly one owner per element
  float y = y0[row * ND + d];
  out[row * ND + d] = y;

  // f(yi) = tanh(yi @ W1 + b1) @ W2 + b2, scalar slice per thread.
  // Schedule: write yi | B_a | GEMM1, write z | B_b | GEMM2, write partials |
  //           B_c | reduce.  (All cross-feval hazards covered by B_a/B_b/B_c.)
  auto feval = [&](float yiv) -> float {
    sYI[wv * YIS + d] = yiv;
    __syncthreads();                      // B_a: yi visible; z/sRed writable

    // ---- GEMM1: z[j1][r] partial over d in [dh*32, dh*32+32) ----
    float z[ROWS];
#pragma unroll
    for (int r = 0; r < ROWS; ++r) z[r] = dh ? 0.0f : b1j;
#pragma unroll
    for (int db = 0; db < 8; ++db) {
      const float wa = w1c[db * 4 + 0];
      const float wb = w1c[db * 4 + 1];
      const float wc = w1c[db * 4 + 2];
      const float wd = w1c[db * 4 + 3];
#pragma unroll
      for (int r = 0; r < ROWS; ++r) {
        const float4 a = *(const float4*)&sYI[r * YIS + dh * 32 + db * 4];
        z[r] = fmaf(a.x, wa, z[r]);
        z[r] = fmaf(a.y, wb, z[r]);
        z[r] = fmaf(a.z, wc, z[r]);
        z[r] = fmaf(a.w, wd, z[r]);
      }
    }
    // combine the two d-halves (lane pairs); bitwise-deterministic (a+b==b+a)
#pragma unroll
    for (int r = 0; r < ROWS; ++r) z[r] += __shfl_xor(z[r], 1, 64);
    // dh lane owns rows dh*4..dh*4+3: tanh + write (2-way bank alias = free)
#pragma unroll
    for (int r2 = 0; r2 < 4; ++r2) {
      const int r = dh * 4 + r2;
      sZ[r * ZS + j1] = fast_tanh(z[r]);
    }
    __syncthreads();                      // B_b: z visible

    // ---- GEMM2: partial o[r][d] over j-chunk wv (W2 in registers,
    //      z reads are wave-uniform broadcasts) ----
    float p[ROWS];
#pragma unroll
    for (int r = 0; r < ROWS; ++r) p[r] = 0.0f;
    const float* __restrict__ zb = sZ + wv * 32;
#pragma unroll
    for (int jq = 0; jq < 8; ++jq) {
      const float wa = w2r[jq * 4 + 0];
      const float wb = w2r[jq * 4 + 1];
      const float wc = w2r[jq * 4 + 2];
      const float wd = w2r[jq * 4 + 3];
#pragma unroll
      for (int r = 0; r < ROWS; ++r) {
        const float4 zv = *(const float4*)&zb[r * ZS + jq * 4];
        p[r] = fmaf(zv.x, wa, p[r]);
        p[r] = fmaf(zv.y, wb, p[r]);
        p[r] = fmaf(zv.z, wc, p[r]);
        p[r] = fmaf(zv.w, wd, p[r]);
      }
    }
#pragma unroll
    for (int r = 0; r < ROWS; ++r) sRed[(wv * ROWS + r) * ND + d] = p[r];
    __syncthreads();                      // B_c: partials visible

    // reduce 8 j-chunks for own (row=wv, d); fixed order -> deterministic
    float o = b2d;
#pragma unroll
    for (int c = 0; c < 8; ++c) o += sRed[(c * ROWS + wv) * ND + d];
    return o;
  };

  // Dormand-Prince 5(4) tableau (5th-order solution row)
  const float A10 = (float)(1.0 / 5.0);
  const float A20 = (float)(3.0 / 40.0),      A21 = (float)(9.0 / 40.0);
  const float A30 = (float)(44.0 / 45.0),     A31 = (float)(-56.0 / 15.0),
              A32 = (float)(32.0 / 9.0);
  const float A40 = (float)(19372.0 / 6561.0), A41 = (float)(-25360.0 / 2187.0),
              A42 = (float)(64448.0 / 6561.0), A43 = (float)(-212.0 / 729.0);
  const float A50 = (float)(9017.0 / 3168.0),  A51 = (float)(-355.0 / 33.0),
              A52 = (float)(46732.0 / 5247.0), A53 = (float)(49.0 / 176.0),
              A54 = (float)(-5103.0 / 18656.0);
  const float B0 = (float)(35.0 / 384.0),      B2 = (float)(500.0 / 1113.0),
              B3 = (float)(125.0 / 192.0),     B4 = (float)(-2187.0 / 6784.0),
              B5 = (float)(11.0 / 84.0);

  for (int ti = 0; ti < NT - 1; ++ti) {
    const float dt = (tt[ti + 1] - tt[ti]) * 0.25f;  // /SUBSTEPS, exact pow2
    for (int ss = 0; ss < 4; ++ss) {
      const float k0 = feval(y);

      float yi = fmaf(dt * A10, k0, y);
      const float k1 = feval(yi);

      yi = y;
      yi = fmaf(dt * A20, k0, yi); yi = fmaf(dt * A21, k1, yi);
      const float k2 = feval(yi);

      yi = y;
      yi = fmaf(dt * A30, k0, yi); yi = fmaf(dt * A31, k1, yi);
      yi = fmaf(dt * A32, k2, yi);
      const float k3 = feval(yi);

      yi = y;
      yi = fmaf(dt * A40, k0, yi); yi = fmaf(dt * A41, k1, yi);
      yi = fmaf(dt * A42, k2, yi); yi = fmaf(dt * A43, k3, yi);
      const float k4 = feval(yi);

      yi = y;
      yi = fmaf(dt * A50, k0, yi); yi = fmaf(dt * A51, k1, yi);
      yi = fmaf(dt * A52, k2, yi); yi = fmaf(dt * A53, k3, yi);
      yi = fmaf(dt * A54, k4, yi);
      const float k5 = feval(yi);

      // y_new = y + dt*(B0*k0 + B2*k2 + B3*k3 + B4*k4 + B5*k5)   (B1 = 0)
      y = fmaf(dt * B0, k0, y);
      y = fmaf(dt * B2, k2, y);
      y = fmaf(dt * B3, k3, y);
      y = fmaf(dt * B4, k4, y);
      y = fmaf(dt * B5, k5, y);
    }
    out[(size_t)(ti + 1) * NB * ND + row * ND + d] = y;
  }
}

extern "C" void kernel_launch(void* const* d_in, const int* in_sizes, int n_in,
                              void* d_out, int out_size, void* d_ws, size_t ws_size,
                              hipStream_t stream) {
  const float* y0 = (const float*)d_in[0];
  const float* tt = (const float*)d_in[1];
  const float* W1 = (const float*)d_in[2];
  const float* b1 = (const float*)d_in[3];
  const float* W2 = (const float*)d_in[4];
  const float* b2 = (const float*)d_in[5];
  float* out = (float*)d_out;

  hipLaunchKernelGGL(ode_kernel, dim3(GRID), dim3(THREADS), 0, stream,
                     y0, tt, W1, b1, W2, b2, out);
}

// Round 4
// 8411.274 us; speedup vs baseline: 1.3771x; 1.2033x over previous
//
#include <hip/hip_runtime.h>

#define NB 4096
#define ND 64
#define NH 256
#define NT 50
#define ROWS 8
#define THREADS 512
#define GRID (NB / ROWS)   // 512 blocks -> exactly 2 per CU

// yi layout: [ROWS][2 halves][36] -> halves 36 floats (144B) apart, so the
// two half-wave broadcast b128 reads in GEMM1 hit disjoint bank quads.
#define YIS 72   // yi row stride (floats) = 2*36
#define ZS  260  // z row stride (floats)

__device__ __forceinline__ float fast_tanh(float x) {
  // tanh(x) = 1 - 2/(exp(2x)+1); safe at +-inf
  float e = __expf(2.0f * x);
  return 1.0f - 2.0f * __builtin_amdgcn_rcpf(e + 1.0f);
}

extern "C" __global__ void __launch_bounds__(THREADS)
__attribute__((amdgpu_waves_per_eu(4, 4)))
ode_kernel(const float* __restrict__ y0,
           const float* __restrict__ tt,
           const float* __restrict__ W1,
           const float* __restrict__ b1,
           const float* __restrict__ W2,
           const float* __restrict__ b2,
           float* __restrict__ out)
{
  __shared__ float sYI[ROWS * YIS];        // 576 floats
  __shared__ float sZ[ROWS * ZS];          // 2080 floats
  __shared__ float sRed[8 * ROWS * ND];    // 4096 floats (16 KB)

  const int tid = threadIdx.x;
  // GEMM1 role: hidden column j1, d-half dh
  const int j1 = tid >> 1;
  const int dh = tid & 1;
  // GEMM2/state role: wave id = state row = j-chunk; d = dim
  const int wv = tid >> 6;
  const int d  = tid & 63;
  const int row = (int)blockIdx.x * ROWS + wv;

  // W1 slice in registers: W1[dh*32+dd][j1]
  float w1c[32];
#pragma unroll
  for (int dd = 0; dd < 32; ++dd) w1c[dd] = W1[(dh * 32 + dd) * NH + j1];
  const float b1j = b1[j1];

  // W2 slice in registers: W2[wv*32+jj][d]  (W2 never goes to LDS)
  float w2r[32];
#pragma unroll
  for (int jj = 0; jj < 32; ++jj) w2r[jj] = W2[(wv * 32 + jj) * ND + d];
  const float b2d = b2[d];

  // scalar state: y[row][d], exactly one owner per element
  float y = y0[row * ND + d];
  out[row * ND + d] = y;

  // yi write slot: row wv, half (d>>5), lane (d&31)
  const int yi_woff = wv * YIS + (d >> 5) * 36 + (d & 31);

  // f(yi) = tanh(yi @ W1 + b1) @ W2 + b2, scalar slice per thread.
  // Schedule: write yi | B_a | GEMM1, write z | B_b | GEMM2, write partials |
  //           B_c | reduce.
  auto feval = [&](float yiv) -> float {
    sYI[yi_woff] = yiv;
    __syncthreads();                      // B_a: yi visible; z/sRed writable

    // ---- GEMM1: z[j1][r] partial over d in [dh*32, dh*32+32) ----
    float z[ROWS];
#pragma unroll
    for (int r = 0; r < ROWS; ++r) z[r] = dh ? 0.0f : b1j;
#pragma unroll
    for (int db = 0; db < 8; ++db) {
      const float wa = w1c[db * 4 + 0];
      const float wb = w1c[db * 4 + 1];
      const float wc = w1c[db * 4 + 2];
      const float wd = w1c[db * 4 + 3];
#pragma unroll
      for (int r = 0; r < ROWS; ++r) {
        const float4 a = *(const float4*)&sYI[r * YIS + dh * 36 + db * 4];
        z[r] = fmaf(a.x, wa, z[r]);
        z[r] = fmaf(a.y, wb, z[r]);
        z[r] = fmaf(a.z, wc, z[r]);
        z[r] = fmaf(a.w, wd, z[r]);
      }
    }
    // combine the two d-halves (lane pairs); deterministic (a+b==b+a)
#pragma unroll
    for (int r = 0; r < ROWS; ++r) z[r] += __shfl_xor(z[r], 1, 64);
    // dh lane owns rows dh*4..dh*4+3: tanh + write (2-way bank alias = free)
#pragma unroll
    for (int r2 = 0; r2 < 4; ++r2) {
      const int r = dh * 4 + r2;
      sZ[r * ZS + j1] = fast_tanh(z[r]);
    }
    __syncthreads();                      // B_b: z visible

    // ---- GEMM2: partial o[r][d] over j-chunk wv (W2 in registers,
    //      z reads are full-wave uniform broadcasts) ----
    float p[ROWS];
#pragma unroll
    for (int r = 0; r < ROWS; ++r) p[r] = 0.0f;
    const float* __restrict__ zb = sZ + wv * 32;
#pragma unroll
    for (int jq = 0; jq < 8; ++jq) {
      const float wa = w2r[jq * 4 + 0];
      const float wb = w2r[jq * 4 + 1];
      const float wc = w2r[jq * 4 + 2];
      const float wd = w2r[jq * 4 + 3];
#pragma unroll
      for (int r = 0; r < ROWS; ++r) {
        const float4 zv = *(const float4*)&zb[r * ZS + jq * 4];
        p[r] = fmaf(zv.x, wa, p[r]);
        p[r] = fmaf(zv.y, wb, p[r]);
        p[r] = fmaf(zv.z, wc, p[r]);
        p[r] = fmaf(zv.w, wd, p[r]);
      }
    }
#pragma unroll
    for (int r = 0; r < ROWS; ++r) sRed[(wv * ROWS + r) * ND + d] = p[r];
    __syncthreads();                      // B_c: partials visible

    // reduce 8 j-chunks for own (row=wv, d); fixed order -> deterministic
    float o = b2d;
#pragma unroll
    for (int c = 0; c < 8; ++c) o += sRed[(c * ROWS + wv) * ND + d];
    return o;
  };

  // Dormand-Prince 5(4) tableau (5th-order solution row)
  const float A10 = (float)(1.0 / 5.0);
  const float A20 = (float)(3.0 / 40.0),      A21 = (float)(9.0 / 40.0);
  const float A30 = (float)(44.0 / 45.0),     A31 = (float)(-56.0 / 15.0),
              A32 = (float)(32.0 / 9.0);
  const float A40 = (float)(19372.0 / 6561.0), A41 = (float)(-25360.0 / 2187.0),
              A42 = (float)(64448.0 / 6561.0), A43 = (float)(-212.0 / 729.0);
  const float A50 = (float)(9017.0 / 3168.0),  A51 = (float)(-355.0 / 33.0),
              A52 = (float)(46732.0 / 5247.0), A53 = (float)(49.0 / 176.0),
              A54 = (float)(-5103.0 / 18656.0);
  const float B0 = (float)(35.0 / 384.0),      B2 = (float)(500.0 / 1113.0),
              B3 = (float)(125.0 / 192.0),     B4 = (float)(-2187.0 / 6784.0),
              B5 = (float)(11.0 / 84.0);

  for (int ti = 0; ti < NT - 1; ++ti) {
    const float dt = (tt[ti + 1] - tt[ti]) * 0.25f;  // /SUBSTEPS, exact pow2
    for (int ss = 0; ss < 4; ++ss) {
      const float k0 = feval(y);

      float yi = fmaf(dt * A10, k0, y);
      const float k1 = feval(yi);

      yi = y;
      yi = fmaf(dt * A20, k0, yi); yi = fmaf(dt * A21, k1, yi);
      const float k2 = feval(yi);

      yi = y;
      yi = fmaf(dt * A30, k0, yi); yi = fmaf(dt * A31, k1, yi);
      yi = fmaf(dt * A32, k2, yi);
      const float k3 = feval(yi);

      yi = y;
      yi = fmaf(dt * A40, k0, yi); yi = fmaf(dt * A41, k1, yi);
      yi = fmaf(dt * A42, k2, yi); yi = fmaf(dt * A43, k3, yi);
      const float k4 = feval(yi);

      yi = y;
      yi = fmaf(dt * A50, k0, yi); yi = fmaf(dt * A51, k1, yi);
      yi = fmaf(dt * A52, k2, yi); yi = fmaf(dt * A53, k3, yi);
      yi = fmaf(dt * A54, k4, yi);
      const float k5 = feval(yi);

      // y_new = y + dt*(B0*k0 + B2*k2 + B3*k3 + B4*k4 + B5*k5)   (B1 = 0)
      y = fmaf(dt * B0, k0, y);
      y = fmaf(dt * B2, k2, y);
      y = fmaf(dt * B3, k3, y);
      y = fmaf(dt * B4, k4, y);
      y = fmaf(dt * B5, k5, y);
    }
    out[(size_t)(ti + 1) * NB * ND + row * ND + d] = y;
  }
}

extern "C" void kernel_launch(void* const* d_in, const int* in_sizes, int n_in,
                              void* d_out, int out_size, void* d_ws, size_t ws_size,
                              hipStream_t stream) {
  const float* y0 = (const float*)d_in[0];
  const float* tt = (const float*)d_in[1];
  const float* W1 = (const float*)d_in[2];
  const float* b1 = (const float*)d_in[3];
  const float* W2 = (const float*)d_in[4];
  const float* b2 = (const float*)d_in[5];
  float* out = (float*)d_out;

  hipLaunchKernelGGL(ode_kernel, dim3(GRID), dim3(THREADS), 0, stream,
                     y0, tt, W1, b1, W2, b2, out);
}

// Round 5
// 8160.209 us; speedup vs baseline: 1.4194x; 1.0308x over previous
//
#include <hip/hip_runtime.h>

#define NB 4096
#define ND 64
#define NH 256
#define NT 50
#define ROWS 8
#define THREADS 512
#define GRID (NB / ROWS)   // 512 blocks -> exactly 2 per CU

// yi layout: [ROWS][2 halves][36] -> halves 36 floats (144B) apart, so the
// two half-wave broadcast b128 reads in GEMM1 hit disjoint bank quads.
#define YIS 72   // yi row stride (floats) = 2*36
#define ZS  260  // z row stride (floats)

__device__ __forceinline__ float fast_tanh(float x) {
  // tanh(x) = 1 - 2/(exp(2x)+1); safe at +-inf
  float e = __expf(2.0f * x);
  return 1.0f - 2.0f * __builtin_amdgcn_rcpf(e + 1.0f);
}

// No __launch_bounds__: its macro expansion was fighting amdgpu_waves_per_eu.
// flat_work_group_size(512,512): exact 8-wave workgroups.
// waves_per_eu(2,4): cap occupancy target at 4 waves/EU (grid caps us there
// anyway: 2 blocks/CU x 8 waves / 4 SIMDs), so RA has no incentive to squeeze
// to 64 VGPRs and spill; min 2 -> VGPR cap 256 >> demand ~105.
extern "C" __global__
__attribute__((amdgpu_flat_work_group_size(THREADS, THREADS)))
__attribute__((amdgpu_waves_per_eu(2, 4)))
void ode_kernel(const float* __restrict__ y0,
                const float* __restrict__ tt,
                const float* __restrict__ W1,
                const float* __restrict__ b1,
                const float* __restrict__ W2,
                const float* __restrict__ b2,
                float* __restrict__ out)
{
  __shared__ float sYI[ROWS * YIS];        // 576 floats
  __shared__ float sZ[ROWS * ZS];          // 2080 floats
  __shared__ float sRed[8 * ROWS * ND];    // 4096 floats (16 KB)

  const int tid = threadIdx.x;
  // GEMM1 role: hidden column j1, d-half dh
  const int j1 = tid >> 1;
  const int dh = tid & 1;
  // GEMM2/state role: wave id = state row = j-chunk; d = dim
  const int wv = tid >> 6;
  const int d  = tid & 63;
  const int row = (int)blockIdx.x * ROWS + wv;

  // W1 slice in registers: W1[dh*32+dd][j1]
  float w1c[32];
#pragma unroll
  for (int dd = 0; dd < 32; ++dd) w1c[dd] = W1[(dh * 32 + dd) * NH + j1];
  const float b1j = b1[j1];

  // W2 slice in registers: W2[wv*32+jj][d]  (W2 never goes to LDS)
  float w2r[32];
#pragma unroll
  for (int jj = 0; jj < 32; ++jj) w2r[jj] = W2[(wv * 32 + jj) * ND + d];
  const float b2d = b2[d];

  // scalar state: y[row][d], exactly one owner per element
  float y = y0[row * ND + d];
  out[row * ND + d] = y;

  // yi write slot: row wv, half (d>>5), lane (d&31)
  const int yi_woff = wv * YIS + (d >> 5) * 36 + (d & 31);

  // f(yi) = tanh(yi @ W1 + b1) @ W2 + b2, scalar slice per thread.
  // Schedule: write yi | B_a | GEMM1, write z | B_b | GEMM2, write partials |
  //           B_c | reduce.
  auto feval = [&](float yiv) -> float {
    sYI[yi_woff] = yiv;
    __syncthreads();                      // B_a: yi visible; z/sRed writable

    // ---- GEMM1: z[j1][r] partial over d in [dh*32, dh*32+32) ----
    float z[ROWS];
#pragma unroll
    for (int r = 0; r < ROWS; ++r) z[r] = dh ? 0.0f : b1j;
#pragma unroll
    for (int db = 0; db < 8; ++db) {
      const float wa = w1c[db * 4 + 0];
      const float wb = w1c[db * 4 + 1];
      const float wc = w1c[db * 4 + 2];
      const float wd = w1c[db * 4 + 3];
#pragma unroll
      for (int r = 0; r < ROWS; ++r) {
        const float4 a = *(const float4*)&sYI[r * YIS + dh * 36 + db * 4];
        z[r] = fmaf(a.x, wa, z[r]);
        z[r] = fmaf(a.y, wb, z[r]);
        z[r] = fmaf(a.z, wc, z[r]);
        z[r] = fmaf(a.w, wd, z[r]);
      }
    }
    // combine the two d-halves (lane pairs); deterministic (a+b==b+a)
#pragma unroll
    for (int r = 0; r < ROWS; ++r) z[r] += __shfl_xor(z[r], 1, 64);
    // dh lane owns rows dh*4..dh*4+3: tanh + write (2-way bank alias = free)
#pragma unroll
    for (int r2 = 0; r2 < 4; ++r2) {
      const int r = dh * 4 + r2;
      sZ[r * ZS + j1] = fast_tanh(z[r]);
    }
    __syncthreads();                      // B_b: z visible

    // ---- GEMM2: partial o[r][d] over j-chunk wv (W2 in registers,
    //      z reads are full-wave uniform broadcasts) ----
    float p[ROWS];
#pragma unroll
    for (int r = 0; r < ROWS; ++r) p[r] = 0.0f;
    const float* __restrict__ zb = sZ + wv * 32;
#pragma unroll
    for (int jq = 0; jq < 8; ++jq) {
      const float wa = w2r[jq * 4 + 0];
      const float wb = w2r[jq * 4 + 1];
      const float wc = w2r[jq * 4 + 2];
      const float wd = w2r[jq * 4 + 3];
#pragma unroll
      for (int r = 0; r < ROWS; ++r) {
        const float4 zv = *(const float4*)&zb[r * ZS + jq * 4];
        p[r] = fmaf(zv.x, wa, p[r]);
        p[r] = fmaf(zv.y, wb, p[r]);
        p[r] = fmaf(zv.z, wc, p[r]);
        p[r] = fmaf(zv.w, wd, p[r]);
      }
    }
#pragma unroll
    for (int r = 0; r < ROWS; ++r) sRed[(wv * ROWS + r) * ND + d] = p[r];
    __syncthreads();                      // B_c: partials visible

    // reduce 8 j-chunks for own (row=wv, d); fixed order -> deterministic
    float o = b2d;
#pragma unroll
    for (int c = 0; c < 8; ++c) o += sRed[(c * ROWS + wv) * ND + d];
    return o;
  };

  // Dormand-Prince 5(4) tableau (5th-order solution row)
  const float A10 = (float)(1.0 / 5.0);
  const float A20 = (float)(3.0 / 40.0),      A21 = (float)(9.0 / 40.0);
  const float A30 = (float)(44.0 / 45.0),     A31 = (float)(-56.0 / 15.0),
              A32 = (float)(32.0 / 9.0);
  const float A40 = (float)(19372.0 / 6561.0), A41 = (float)(-25360.0 / 2187.0),
              A42 = (float)(64448.0 / 6561.0), A43 = (float)(-212.0 / 729.0);
  const float A50 = (float)(9017.0 / 3168.0),  A51 = (float)(-355.0 / 33.0),
              A52 = (float)(46732.0 / 5247.0), A53 = (float)(49.0 / 176.0),
              A54 = (float)(-5103.0 / 18656.0);
  const float B0 = (float)(35.0 / 384.0),      B2 = (float)(500.0 / 1113.0),
              B3 = (float)(125.0 / 192.0),     B4 = (float)(-2187.0 / 6784.0),
              B5 = (float)(11.0 / 84.0);

  for (int ti = 0; ti < NT - 1; ++ti) {
    const float dt = (tt[ti + 1] - tt[ti]) * 0.25f;  // /SUBSTEPS, exact pow2
    for (int ss = 0; ss < 4; ++ss) {
      const float k0 = feval(y);

      float yi = fmaf(dt * A10, k0, y);
      const float k1 = feval(yi);

      yi = y;
      yi = fmaf(dt * A20, k0, yi); yi = fmaf(dt * A21, k1, yi);
      const float k2 = feval(yi);

      yi = y;
      yi = fmaf(dt * A30, k0, yi); yi = fmaf(dt * A31, k1, yi);
      yi = fmaf(dt * A32, k2, yi);
      const float k3 = feval(yi);

      yi = y;
      yi = fmaf(dt * A40, k0, yi); yi = fmaf(dt * A41, k1, yi);
      yi = fmaf(dt * A42, k2, yi); yi = fmaf(dt * A43, k3, yi);
      const float k4 = feval(yi);

      yi = y;
      yi = fmaf(dt * A50, k0, yi); yi = fmaf(dt * A51, k1, yi);
      yi = fmaf(dt * A52, k2, yi); yi = fmaf(dt * A53, k3, yi);
      yi = fmaf(dt * A54, k4, yi);
      const float k5 = feval(yi);

      // y_new = y + dt*(B0*k0 + B2*k2 + B3*k3 + B4*k4 + B5*k5)   (B1 = 0)
      y = fmaf(dt * B0, k0, y);
      y = fmaf(dt * B2, k2, y);
      y = fmaf(dt * B3, k3, y);
      y = fmaf(dt * B4, k4, y);
      y = fmaf(dt * B5, k5, y);
    }
    out[(size_t)(ti + 1) * NB * ND + row * ND + d] = y;
  }
}

extern "C" void kernel_launch(void* const* d_in, const int* in_sizes, int n_in,
                              void* d_out, int out_size, void* d_ws, size_t ws_size,
                              hipStream_t stream) {
  const float* y0 = (const float*)d_in[0];
  const float* tt = (const float*)d_in[1];
  const float* W1 = (const float*)d_in[2];
  const float* b1 = (const float*)d_in[3];
  const float* W2 = (const float*)d_in[4];
  const float* b2 = (const float*)d_in[5];
  float* out = (float*)d_out;

  hipLaunchKernelGGL(ode_kernel, dim3(GRID), dim3(THREADS), 0, stream,
                     y0, tt, W1, b1, W2, b2, out);
}